// Round 1
// baseline (177.810 us; speedup 1.0000x reference)
//
#include <hip/hip_runtime.h>

// Fused polyphase resample (UP=3, DOWN=2, 63-tap prototype h with 2-zero prepad)
// + 51-tap causal FIR.
//
//   u[t]  = sum_{i=0..20} h[p0+3i] * x[q-i],  s=2t+32, p0=s%3, q=s/3
//           (u[t]=0 for t<0 or t>=n_out; x[] zero outside [0,n_in))
//   out[o]= sum_{m=0..50} b[m] * u[o-m]
//
// One block = 256 outputs. Stages x halo (<=225 values) and 306 u values in LDS.

#define TILE 256
#define XTILE 232
#define UTILE (TILE + 50) // 306

__global__ __launch_bounds__(256) void fused_resample_fir(
    const float* __restrict__ x, const float* __restrict__ h,
    const float* __restrict__ b, float* __restrict__ out,
    int n_in, int n_out, int out_size)
{
    __shared__ float h_s[64];
    __shared__ float b_s[52];
    __shared__ float x_s[XTILE];
    __shared__ float u_s[UTILE];

    const int j = threadIdx.x;
    const int o0 = blockIdx.x * TILE;
    const int t_min = o0 - 50;

    if (j < 63) h_s[j] = h[j];
    if (j < 51) b_s[j] = b[j];

    // xbase = floor((2*t_min + 32)/3) - 20  (floor division, t_min may be negative)
    const int a = 2 * t_min + 32;
    const int xbase = ((a >= 0) ? (a / 3) : -((-a + 2) / 3)) - 20;

    if (j < XTILE) {
        const int xi = xbase + j;
        x_s[j] = (xi >= 0 && xi < n_in) ? x[xi] : 0.0f;
    }
    __syncthreads();

    // u values for t in [t_min, t_min + UTILE)
    for (int jj = j; jj < UTILE; jj += TILE) {
        const int t = t_min + jj;
        float acc = 0.0f;
        if (t >= 0 && t < n_out) {
            const int s  = 2 * t + 32;   // >= 32, safe for % and /
            const int p0 = s % 3;
            const int q  = s / 3;
            const int base = q - xbase;  // in [20, 224]
#pragma unroll
            for (int i = 0; i < 21; ++i) {
                acc += h_s[p0 + 3 * i] * x_s[base - i];
            }
        }
        u_s[jj] = acc;
    }
    __syncthreads();

    const int o = o0 + j;
    if (o < out_size) {
        // u index (o-m) - t_min = j + 50 - m  ->  spans [j, j+50]
        float acc = 0.0f;
#pragma unroll
        for (int m = 0; m <= 50; ++m) {
            acc += b_s[m] * u_s[j + 50 - m];
        }
        out[o] = acc;
    }
}

extern "C" void kernel_launch(void* const* d_in, const int* in_sizes, int n_in_arrs,
                              void* d_out, int out_size, void* d_ws, size_t ws_size,
                              hipStream_t stream) {
    const float* x = (const float*)d_in[0];
    const float* h = (const float*)d_in[1];
    const float* b = (const float*)d_in[2];
    float* out = (float*)d_out;

    const int n_in  = in_sizes[0];                       // 8388608
    const int n_out = (int)((long long)n_in * 3 / 2);    // 12582912

    const int nblocks = (out_size + TILE - 1) / TILE;    // 49153
    fused_resample_fir<<<nblocks, TILE, 0, stream>>>(x, h, b, out, n_in, n_out, out_size);
}